// Round 17
// baseline (229.887 us; speedup 1.0000x reference)
//
#include <hip/hip_runtime.h>
#include <math.h>

// Problem constants
#define QN 4096
#define MN 65536
#define DN 384
#define CN 128
#define NCHUNK 64                 // m-chunks
#define MROWS_PER_CHUNK (MN / NCHUNK)   // 1024
#define MT_PER (MROWS_PER_CHUNK / 64)   // 16 m-tiles (64 rows) per block
// fp4 fragment-major for 32x32x64: one fragment block = 64 lanes x 16B = 1KB
#define FRAG_B 1024
#define GSTRIDE6 (6 * FRAG_B)           // bytes per 32-row group (6 kc) = 6144
#define TSTRIDE32 (2 * GSTRIDE6)        // bytes per 64-row tile = 12288

typedef __attribute__((ext_vector_type(8))) int i32x8;
typedef __attribute__((ext_vector_type(4))) int i32x4;
typedef __attribute__((ext_vector_type(16))) float f32x16;

// e2m1 fp4 encode (nearest): levels 0,0.5,1,1.5,2,3,4,6; bit3 = sign.
__device__ __forceinline__ unsigned fp4e(float x) {
  const float a = fabsf(x);
  unsigned c = (unsigned)(a >= 0.25f) + (a >= 0.75f) + (a >= 1.25f) +
               (a >= 1.75f) + (a >= 2.5f) + (a >= 3.5f) + (a >= 5.0f);
  return ((x < 0.f) ? 8u : 0u) | c;
}

// ------- Kernel A: L2-normalize rows; q AND m -> fp4 32x32x64 frag-major ---
// 32x32x64 fp4 operand image (extrapolating the R14/R15-VERIFIED 16x16
// pattern row=lane&(M-1), K-slice=(lane>>log2 M)*32 nibbles): fragment lane
// fl holds row (fl&31), K nibbles [kc*64 + (fl>>5)*32 .. +32), k-even low.
// Row r, element k = 2*lane + 128*i: kc = (lane>>5) + 2*i,
// fl = ((lane>>4)&1)*32 + (r&31), byte = lane&15. Value x16 (MFMA scale
// 2^-4 undoes). Same bytes/row (192) as R15 -> same buffer sizes.
__global__ __launch_bounds__(256) void nrm_kernel(const float* __restrict__ qe,
                                                  const float* __restrict__ me,
                                                  unsigned char* __restrict__ yq,
                                                  unsigned char* __restrict__ ym) {
  const int row = blockIdx.x * 4 + (threadIdx.x >> 6);
  const int lane = threadIdx.x & 63;
  const int isq = (row < QN);
  const int r = isq ? row : row - QN;
  const float* xr = isq ? qe + (size_t)r * DN : me + (size_t)r * DN;
  unsigned char* yb = isq ? yq : ym;
  float2 v[3];
  float ss = 0.f;
#pragma unroll
  for (int i = 0; i < 3; ++i) {
    v[i] = *(const float2*)&xr[lane * 2 + i * 128];
    ss += v[i].x * v[i].x + v[i].y * v[i].y;
  }
#pragma unroll
  for (int m = 1; m < 64; m <<= 1) ss += __shfl_xor(ss, m);
  const float s16 = (16.0f / fmaxf(sqrtf(ss), 1e-8f));
  const int g32 = r >> 5;
  const int fl = ((lane >> 4) & 1) * 32 + (r & 31);
  const int kcb = lane >> 5;               // kc = kcb + 2*i
#pragma unroll
  for (int i = 0; i < 3; ++i) {
    const unsigned b = fp4e(v[i].x * s16) | (fp4e(v[i].y * s16) << 4);
    yb[((size_t)(g32 * 6 + kcb + 2 * i) * 64 + fl) * 16 + (lane & 15)] =
        (unsigned char)b;
  }
}

// ------- Kernel B: MX fp4xfp4 32x32x64 GEMM, barrier-free ------------------
// R17: R15/R16 showed the gemm (~54 µs) is SIMD-issue-bound at the 16x16
// rate, insensitive to prefetch depth. 32x32x64 fp4: 1.26x MFMA rate (9099
// vs 7228 TF, m59) AND half the MFMA instructions (12/tile/wave). K-halves
// (kc 0-2 in pre, 3-5 in b1) accumulate into ONE acc per output tile; the
// ct-split prefetch cadence is retained. Zero barriers, zero LDS in loop.
// C/D map (HW-verified m74/m101): col=lane&31, row=(reg&3)+8*(reg>>2)+
// 4*(lane>>5). Wave = 64q x 32m; rt in {0,1} = 32-row halves.
__global__ __launch_bounds__(256, 2) void gemm_max_kernel(
    const unsigned char* __restrict__ qn4, const unsigned char* __restrict__ mn4,
    float* __restrict__ pmax) {
  __shared__ float smax[2][128];

  const int tid = threadIdx.x;
  const int wave = tid >> 6, lane = tid & 63;
  const int wr = wave >> 1, wc = wave & 1;   // waves: 2x2 over 128q x 64m

  // --- XCD-partitioned bijective swizzle (HW assigns XCD = linear id % 8) ---
  const int bid = blockIdx.y * gridDim.x + blockIdx.x;  // linear dispatch id
  const int xcd = bid & 7;
  const int j = bid >> 3;                    // 0..255 within this XCD
  const int ychunk = (xcd << 3) | (j >> 5);  // 8 m-chunks per XCD
  const int qrow0 = (j & 31) * 128;          // x sweeps fastest
  const int mchunk0 = ychunk * MROWS_PER_CHUNK;

  float rmax[32];
#pragma unroll
  for (int i = 0; i < 32; ++i) rmax[i] = -3.0e38f;

  // ---- A fragments direct from global (fragment-major, L2-resident) -------
  const int gq0 = (qrow0 >> 5) + wr * 2;     // 32-row group of rt=0
  i32x8 afr[6][2];
#pragma unroll
  for (int kc = 0; kc < 6; ++kc)
#pragma unroll
    for (int rt = 0; rt < 2; ++rt) {
      afr[kc][rt] = (i32x8){0, 0, 0, 0, 0, 0, 0, 0};
      i32x4 t = *(const i32x4*)(qn4 +
          ((size_t)((gq0 + rt) * 6 + kc) * 64 + lane) * 16);
      afr[kc][rt][0] = t[0]; afr[kc][rt][1] = t[1];
      afr[kc][rt][2] = t[2]; afr[kc][rt][3] = t[3];
    }

  // --- per-wave fragment-major fp4 B pointers (32 m-cols per wave) ---------
  const int gm0 = (mchunk0 >> 5) + wc;
  const unsigned char* bp = mn4 + ((size_t)gm0 * 6 * 64 + lane) * 16;  // kc0
  const unsigned char* bq = bp + 3 * FRAG_B;  // kc3 of tile mt

  i32x8 pre[3], b1[3];
#pragma unroll
  for (int kc = 0; kc < 3; ++kc) {
    pre[kc] = (i32x8){0, 0, 0, 0, 0, 0, 0, 0};
    b1[kc] = (i32x8){0, 0, 0, 0, 0, 0, 0, 0};
  }
  // prologue: load kc0..2 of tile 0 into pre; bp then runs one tile ahead
#pragma unroll
  for (int kc = 0; kc < 3; ++kc) {
    i32x4 t = *(const i32x4*)(bp + kc * FRAG_B);
    pre[kc][0] = t[0]; pre[kc][1] = t[1]; pre[kc][2] = t[2]; pre[kc][3] = t[3];
  }
  bp += TSTRIDE32;

#pragma unroll 1
  for (int mt = 0; mt < MT_PER; ++mt) {
    // issue kc3..5(mt) loads (consumed in cluster B, covered by cluster A)
#pragma unroll
    for (int kc = 0; kc < 3; ++kc) {
      i32x4 t = *(const i32x4*)(bq + kc * FRAG_B);
      b1[kc][0] = t[0]; b1[kc][1] = t[1]; b1[kc][2] = t[2]; b1[kc][3] = t[3];
    }
    bq += TSTRIDE32;
    __builtin_amdgcn_sched_barrier(0);   // keep load issue above cluster A

    f32x16 acc0 = (f32x16)(0.f), acc1 = (f32x16)(0.f);

    // ---- cluster A: kc0..2 on pre (loaded one cluster ago; no wait) -------
    __builtin_amdgcn_s_setprio(1);
#pragma unroll
    for (int kc = 0; kc < 3; ++kc) {
      acc0 = __builtin_amdgcn_mfma_scale_f32_32x32x64_f8f6f4(
          afr[kc][0], pre[kc], acc0, 4, 4,   // A fp4, B fp4
          0, 0x7b7b7b7b, 0, 0x7b7b7b7b);     // both scales 2^-4
      acc1 = __builtin_amdgcn_mfma_scale_f32_32x32x64_f8f6f4(
          afr[kc][1], pre[kc], acc1, 4, 4,
          0, 0x7b7b7b7b, 0, 0x7b7b7b7b);
    }
    __builtin_amdgcn_s_setprio(0);
    __builtin_amdgcn_sched_barrier(0);   // cluster A stays above pre reload

    // issue kc0..2(mt+1) into pre (consumed next iter's cluster A)
    if (mt + 1 < MT_PER) {
#pragma unroll
      for (int kc = 0; kc < 3; ++kc) {
        i32x4 t = *(const i32x4*)(bp + kc * FRAG_B);
        pre[kc][0] = t[0]; pre[kc][1] = t[1];
        pre[kc][2] = t[2]; pre[kc][3] = t[3];
      }
      bp += TSTRIDE32;
    }
    __builtin_amdgcn_sched_barrier(0);   // keep pre issue above cluster B

    // ---- cluster B: kc3..5 on b1 (same acc — full K accumulated) ----------
    __builtin_amdgcn_s_setprio(1);
#pragma unroll
    for (int kc = 0; kc < 3; ++kc) {
      acc0 = __builtin_amdgcn_mfma_scale_f32_32x32x64_f8f6f4(
          afr[kc + 3][0], b1[kc], acc0, 4, 4,
          0, 0x7b7b7b7b, 0, 0x7b7b7b7b);
      acc1 = __builtin_amdgcn_mfma_scale_f32_32x32x64_f8f6f4(
          afr[kc + 3][1], b1[kc], acc1, 4, 4,
          0, 0x7b7b7b7b, 0, 0x7b7b7b7b);
    }
    __builtin_amdgcn_s_setprio(0);

#pragma unroll
    for (int r = 0; r < 16; ++r) {
      rmax[r] = fmaxf(rmax[r], acc0[r]);
      rmax[16 + r] = fmaxf(rmax[16 + r], acc1[r]);
    }
  }

  // ---- epilogue: reduce over m-cols (lanes&31), write per-q-row maxes -----
#pragma unroll
  for (int i = 0; i < 32; ++i) {
    float v = rmax[i];
    v = fmaxf(v, __shfl_xor(v, 1));
    v = fmaxf(v, __shfl_xor(v, 2));
    v = fmaxf(v, __shfl_xor(v, 4));
    v = fmaxf(v, __shfl_xor(v, 8));
    v = fmaxf(v, __shfl_xor(v, 16));
    rmax[i] = v;
  }
  if ((lane & 31) == 0) {
    const int h4 = (lane >> 5) * 4;          // row offset of this lane-half
#pragma unroll
    for (int rt = 0; rt < 2; ++rt)
#pragma unroll
      for (int reg = 0; reg < 16; ++reg) {
        const int qiw = rt * 32 + (reg & 3) + 8 * (reg >> 2) + h4;
        smax[wc][wr * 64 + qiw] = rmax[rt * 16 + reg];
      }
  }
  __syncthreads();
  if (tid < 128) {
    const float v = fmaxf(smax[0][tid], smax[1][tid]);
    pmax[(size_t)(qrow0 + tid) * NCHUNK + ychunk] = v;
  }
}

// ------- Kernel C: reduce partials; uniform row OR exact fp32 re-check -----
__global__ __launch_bounds__(256) void decide_kernel(
    const float* __restrict__ pmax, const float* __restrict__ qe,
    const float* __restrict__ me, const float* __restrict__ labels,
    float* __restrict__ out) {
  const int q = blockIdx.x;
  const int t = threadIdx.x;  // 256
  __shared__ float smx;
  if (t < 64) {
    float v = pmax[(size_t)q * NCHUNK + t];  // NCHUNK == 64
#pragma unroll
    for (int m = 1; m < 64; m <<= 1) v = fmaxf(v, __shfl_xor(v, m));
    if (t == 0) smx = v;
  }
  __syncthreads();
  if (smx <= 0.5f) {  // uniform fast path (expected for all queries)
    if (t < CN) out[(size_t)q * CN + t] = 1.0f / 128.0f;
    return;
  }
  // exact fp32 path (rare / borderline queries only)
  __shared__ float sred[256];
  __shared__ int sidx[256];
  __shared__ float wsum[4];
  const float* qr = qe + (size_t)q * DN;
  float ss = 0.f;
  for (int i = t; i < DN; i += 256) ss += qr[i] * qr[i];
#pragma unroll
  for (int m = 1; m < 64; m <<= 1) ss += __shfl_xor(ss, m);
  if ((t & 63) == 0) wsum[t >> 6] = ss;
  __syncthreads();
  const float qnorm = fmaxf(sqrtf(wsum[0] + wsum[1] + wsum[2] + wsum[3]), 1e-8f);

  float best = -3.0e38f;
  int bidx = 0x7fffffff;
  for (int j = t; j < MN; j += 256) {
    const float* mr = me + (size_t)j * DN;
    float dot = 0.f, ms = 0.f;
    for (int k = 0; k < DN; ++k) {
      float a = qr[k], b = mr[k];
      dot += a * b;
      ms += b * b;
    }
    const float sim = dot / (qnorm * fmaxf(sqrtf(ms), 1e-8f));
    if (sim > best) { best = sim; bidx = j; }  // strict > keeps first index
  }
  sred[t] = best;
  sidx[t] = bidx;
  __syncthreads();
  for (int s = 128; s > 0; s >>= 1) {
    if (t < s) {
      const float ov = sred[t + s];
      const int oi = sidx[t + s];
      if (ov > sred[t] || (ov == sred[t] && oi < sidx[t])) {
        sred[t] = ov;
        sidx[t] = oi;
      }
    }
    __syncthreads();
  }
  const float mx = sred[0];
  const int mi = sidx[0];
  if (t < CN)
    out[(size_t)q * CN + t] =
        (mx > 0.7f) ? labels[(size_t)mi * CN + t] : (1.0f / 128.0f);
}

extern "C" void kernel_launch(void* const* d_in, const int* in_sizes, int n_in,
                              void* d_out, int out_size, void* d_ws,
                              size_t ws_size, hipStream_t stream) {
  const float* qe = (const float*)d_in[0];  // [4096,384] f32
  const float* me = (const float*)d_in[1];  // [65536,384] f32
  const float* lb = (const float*)d_in[2];  // [65536,128] f32
  float* out = (float*)d_out;               // [4096,128] f32

  char* ws = (char*)d_ws;
  const size_t OFF_QN = 0;                  // qn4: 4096*192 = 786,432 B
  const size_t OFF_MN = OFF_QN + (size_t)QN * DN;        // mn4: 65536*192 B
  const size_t OFF_PMAX = OFF_MN + (size_t)MN * DN;      // (offsets roomy)
  unsigned char* qn4 = (unsigned char*)(ws + OFF_QN);    // fp4 frag-major 32
  unsigned char* mn4 = (unsigned char*)(ws + OFF_MN);    // fp4 frag-major 32
  float* pmax = (float*)(ws + OFF_PMAX);                 // [4096][64] = 1 MB

  nrm_kernel<<<(QN + MN) / 4, 256, 0, stream>>>(qe, me, qn4, mn4);
  gemm_max_kernel<<<dim3(QN / 128, NCHUNK), 256, 0, stream>>>(qn4, mn4, pmax);
  decide_kernel<<<QN, 256, 0, stream>>>(pmax, qe, me, lb, out);
}

// Round 18
// 211.313 us; speedup vs baseline: 1.0879x; 1.0879x over previous
//
#include <hip/hip_runtime.h>
#include <math.h>

// Problem constants
#define QN 4096
#define MN 65536
#define DN 384
#define CN 128
#define NCHUNK 64                 // m-chunks
#define MROWS_PER_CHUNK (MN / NCHUNK)   // 1024
#define MT_PER (MROWS_PER_CHUNK / 64)   // 16 m-tiles (64 rows) per block
// fp4 fragment-major: one fragment block = 64 lanes x 16B = 1024 B
#define FRAG_B 1024
#define GSTRIDE (3 * FRAG_B)            // bytes per 16-row group (3 kc) = 3072
#define TSTRIDE (4 * GSTRIDE)           // bytes per 64-row tile = 12288

typedef __attribute__((ext_vector_type(8))) int i32x8;
typedef __attribute__((ext_vector_type(4))) int i32x4;
typedef __attribute__((ext_vector_type(4))) float f32x4;

// e2m1 fp4 encode (nearest): levels 0,0.5,1,1.5,2,3,4,6; bit3 = sign.
__device__ __forceinline__ unsigned fp4e(float x) {
  const float a = fabsf(x);
  unsigned c = (unsigned)(a >= 0.25f) + (a >= 0.75f) + (a >= 1.25f) +
               (a >= 1.75f) + (a >= 2.5f) + (a >= 3.5f) + (a >= 5.0f);
  return ((x < 0.f) ? 8u : 0u) | c;
}

// ------- Kernel A: L2-normalize rows; BOTH q and m -> fp4 fragment-major ---
// (R15 verbatim — the best verified configuration, absmax 0.0.)
// Fragment-major = per-lane register image of the 16x16x128 f8f6f4 fp4
// operand: fragment lane fl = quad*16 + (row&15) holds 16 B = K-bytes
// [quad*32 .. +32) as nibbles, k-even low. Value x16; MFMA scale 2^-4
// (0x7b) undoes it.
__global__ __launch_bounds__(256) void nrm_kernel(const float* __restrict__ qe,
                                                  const float* __restrict__ me,
                                                  unsigned char* __restrict__ yq,
                                                  unsigned char* __restrict__ ym) {
  const int row = blockIdx.x * 4 + (threadIdx.x >> 6);
  const int lane = threadIdx.x & 63;
  const int isq = (row < QN);
  const int r = isq ? row : row - QN;
  const float* xr = isq ? qe + (size_t)r * DN : me + (size_t)r * DN;
  unsigned char* yb = isq ? yq : ym;
  float2 v[3];
  float ss = 0.f;
#pragma unroll
  for (int i = 0; i < 3; ++i) {
    v[i] = *(const float2*)&xr[lane * 2 + i * 128];
    ss += v[i].x * v[i].x + v[i].y * v[i].y;
  }
#pragma unroll
  for (int m = 1; m < 64; m <<= 1) ss += __shfl_xor(ss, m);
  const float s16 = (16.0f / fmaxf(sqrtf(ss), 1e-8f));
  const int g = r >> 4;
  const int fl = ((lane >> 4) << 4) + (r & 15);   // fragment lane index
#pragma unroll
  for (int i = 0; i < 3; ++i) {
    const unsigned b = fp4e(v[i].x * s16) | (fp4e(v[i].y * s16) << 4);
    yb[((size_t)(g * 3 + i) * 64 + fl) * 16 + (lane & 15)] = (unsigned char)b;
  }
}

// ------- Kernel B: MX fp4xfp4 16x16x128 GEMM, barrier-free (R15, BEST) -----
// Session ledger at this kernel:
//   R16 (4-buffer deeper prefetch): NEUTRAL -> not latency-bound.
//   R17 (32x32x64 shape): -8% -> AGPR init/extract VALU (accvgpr round-trips,
//        VALUBusy 54%) swamps the 1.26x rate gain at per-tile K=384.
// Remaining gap (gemm ~54 µs vs 28.5 µs fp4 MFMA floor) = SIMD issue-port
// sharing MFMA + irreducible per-tile max-extraction VALU (this op is
// max-GEMM: every sim transits one fmax) + regalloc AGPR moves — not
// addressable at HIP source level (two structural attempts failed).
// Total floor ~= 158 µs fixed harness (2x ~400MB ws fills @59.7 + nrm ~20 at
// HBM floor + decide ~5) + gemm; R15 total 212.7 µs.
__global__ __launch_bounds__(256, 2) void gemm_max_kernel(
    const unsigned char* __restrict__ qn4, const unsigned char* __restrict__ mn4,
    float* __restrict__ pmax) {
  __shared__ float smax[2][128];

  const int tid = threadIdx.x;
  const int wave = tid >> 6, lane = tid & 63;
  const int wr = wave >> 1, wc = wave & 1;   // waves: 2x2 over 128q x 64m
  const int quad = lane >> 4, l16 = lane & 15;

  // --- XCD-partitioned bijective swizzle (HW assigns XCD = linear id % 8) ---
  const int bid = blockIdx.y * gridDim.x + blockIdx.x;  // linear dispatch id
  const int xcd = bid & 7;
  const int j = bid >> 3;                    // 0..255 within this XCD
  const int ychunk = (xcd << 3) | (j >> 5);  // 8 m-chunks per XCD
  const int qrow0 = (j & 31) * 128;          // x sweeps fastest
  const int mchunk0 = ychunk * MROWS_PER_CHUNK;

  float rmax[16];
#pragma unroll
  for (int i = 0; i < 16; ++i) rmax[i] = -3.0e38f;

  // ---- A fragments direct from global (fragment-major, L2-resident) -------
  const int gq0 = (qrow0 >> 4) + wr * 4;     // 16-row group of rt=0
  i32x8 afr[3][4];
#pragma unroll
  for (int kc = 0; kc < 3; ++kc)
#pragma unroll
    for (int rt = 0; rt < 4; ++rt) {
      afr[kc][rt] = (i32x8){0, 0, 0, 0, 0, 0, 0, 0};
      i32x4 t = *(const i32x4*)(qn4 +
          ((size_t)((gq0 + rt) * 3 + kc) * 64 + lane) * 16);
      afr[kc][rt][0] = t[0]; afr[kc][rt][1] = t[1];
      afr[kc][rt][2] = t[2]; afr[kc][rt][3] = t[3];
    }

  // --- per-wave fragment-major fp4 B pointers (ct0 -> g0, ct1 -> g0+1) -----
  const int g0 = (mchunk0 >> 4) + wc * 2;
  const unsigned char* bp0 = mn4 + ((size_t)g0 * 3 * 64 + lane) * 16;  // ct0
  const unsigned char* bp1 = bp0 + GSTRIDE;                            // ct1

  i32x8 pre[3], b1[3];
#pragma unroll
  for (int kc = 0; kc < 3; ++kc) {
    pre[kc] = (i32x8){0, 0, 0, 0, 0, 0, 0, 0};
    b1[kc] = (i32x8){0, 0, 0, 0, 0, 0, 0, 0};
  }
  // prologue: load ct0 of tile 0 into pre; bp0 then runs one tile ahead
#pragma unroll
  for (int kc = 0; kc < 3; ++kc) {
    i32x4 t = *(const i32x4*)(bp0 + kc * FRAG_B);
    pre[kc][0] = t[0]; pre[kc][1] = t[1]; pre[kc][2] = t[2]; pre[kc][3] = t[3];
  }
  bp0 += TSTRIDE;

#pragma unroll 1
  for (int mt = 0; mt < MT_PER; ++mt) {
    // issue ct1(mt) loads (consumed in cluster B, covered by cluster A)
#pragma unroll
    for (int kc = 0; kc < 3; ++kc) {
      i32x4 t = *(const i32x4*)(bp1 + kc * FRAG_B);
      b1[kc][0] = t[0]; b1[kc][1] = t[1]; b1[kc][2] = t[2]; b1[kc][3] = t[3];
    }
    bp1 += TSTRIDE;
    __builtin_amdgcn_sched_barrier(0);   // keep load issue above cluster A

    // ---- cluster A: ct0 MFMAs on pre (loaded one cluster ago; no wait) ----
    {
      f32x4 acc[4];
#pragma unroll
      for (int rt = 0; rt < 4; ++rt) acc[rt] = (f32x4){0.f, 0.f, 0.f, 0.f};
      __builtin_amdgcn_s_setprio(1);
#pragma unroll
      for (int kc = 0; kc < 3; ++kc)
#pragma unroll
        for (int rt = 0; rt < 4; ++rt)
          acc[rt] = __builtin_amdgcn_mfma_scale_f32_16x16x128_f8f6f4(
              afr[kc][rt], pre[kc], acc[rt], 4, 4,  // A fp4, B fp4
              0, 0x7b7b7b7b, 0, 0x7b7b7b7b);        // both scales 2^-4
      __builtin_amdgcn_s_setprio(0);
#pragma unroll
      for (int rt = 0; rt < 4; ++rt)
#pragma unroll
        for (int r = 0; r < 4; ++r)
          rmax[rt * 4 + r] = fmaxf(rmax[rt * 4 + r], acc[rt][r]);
    }
    __builtin_amdgcn_sched_barrier(0);   // cluster A stays above pre reload

    // issue ct0(mt+1) into pre (consumed next iter's cluster A)
    if (mt + 1 < MT_PER) {
#pragma unroll
      for (int kc = 0; kc < 3; ++kc) {
        i32x4 t = *(const i32x4*)(bp0 + kc * FRAG_B);
        pre[kc][0] = t[0]; pre[kc][1] = t[1];
        pre[kc][2] = t[2]; pre[kc][3] = t[3];
      }
      bp0 += TSTRIDE;
    }
    __builtin_amdgcn_sched_barrier(0);   // keep pre issue above cluster B

    // ---- cluster B: ct1 MFMAs on b1 -----------------------------------
    {
      f32x4 acc[4];
#pragma unroll
      for (int rt = 0; rt < 4; ++rt) acc[rt] = (f32x4){0.f, 0.f, 0.f, 0.f};
      __builtin_amdgcn_s_setprio(1);
#pragma unroll
      for (int kc = 0; kc < 3; ++kc)
#pragma unroll
        for (int rt = 0; rt < 4; ++rt)
          acc[rt] = __builtin_amdgcn_mfma_scale_f32_16x16x128_f8f6f4(
              afr[kc][rt], b1[kc], acc[rt], 4, 4,   // A fp4, B fp4
              0, 0x7b7b7b7b, 0, 0x7b7b7b7b);        // both scales 2^-4
      __builtin_amdgcn_s_setprio(0);
#pragma unroll
      for (int rt = 0; rt < 4; ++rt)
#pragma unroll
        for (int r = 0; r < 4; ++r)
          rmax[rt * 4 + r] = fmaxf(rmax[rt * 4 + r], acc[rt][r]);
    }
  }

#pragma unroll
  for (int i = 0; i < 16; ++i) {
    float v = rmax[i];
    v = fmaxf(v, __shfl_xor(v, 1));
    v = fmaxf(v, __shfl_xor(v, 2));
    v = fmaxf(v, __shfl_xor(v, 4));
    v = fmaxf(v, __shfl_xor(v, 8));
    rmax[i] = v;
  }
  if (l16 == 0) {
#pragma unroll
    for (int rt = 0; rt < 4; ++rt)
#pragma unroll
      for (int r = 0; r < 4; ++r)
        smax[wc][wr * 64 + rt * 16 + quad * 4 + r] = rmax[rt * 4 + r];
  }
  __syncthreads();
  if (tid < 128) {
    const float v = fmaxf(smax[0][tid], smax[1][tid]);
    pmax[(size_t)(qrow0 + tid) * NCHUNK + ychunk] = v;
  }
}

// ------- Kernel C: reduce partials; uniform row OR exact fp32 re-check -----
__global__ __launch_bounds__(256) void decide_kernel(
    const float* __restrict__ pmax, const float* __restrict__ qe,
    const float* __restrict__ me, const float* __restrict__ labels,
    float* __restrict__ out) {
  const int q = blockIdx.x;
  const int t = threadIdx.x;  // 256
  __shared__ float smx;
  if (t < 64) {
    float v = pmax[(size_t)q * NCHUNK + t];  // NCHUNK == 64
#pragma unroll
    for (int m = 1; m < 64; m <<= 1) v = fmaxf(v, __shfl_xor(v, m));
    if (t == 0) smx = v;
  }
  __syncthreads();
  if (smx <= 0.5f) {  // uniform fast path (expected for all queries)
    if (t < CN) out[(size_t)q * CN + t] = 1.0f / 128.0f;
    return;
  }
  // exact fp32 path (rare / borderline queries only)
  __shared__ float sred[256];
  __shared__ int sidx[256];
  __shared__ float wsum[4];
  const float* qr = qe + (size_t)q * DN;
  float ss = 0.f;
  for (int i = t; i < DN; i += 256) ss += qr[i] * qr[i];
#pragma unroll
  for (int m = 1; m < 64; m <<= 1) ss += __shfl_xor(ss, m);
  if ((t & 63) == 0) wsum[t >> 6] = ss;
  __syncthreads();
  const float qnorm = fmaxf(sqrtf(wsum[0] + wsum[1] + wsum[2] + wsum[3]), 1e-8f);

  float best = -3.0e38f;
  int bidx = 0x7fffffff;
  for (int j = t; j < MN; j += 256) {
    const float* mr = me + (size_t)j * DN;
    float dot = 0.f, ms = 0.f;
    for (int k = 0; k < DN; ++k) {
      float a = qr[k], b = mr[k];
      dot += a * b;
      ms += b * b;
    }
    const float sim = dot / (qnorm * fmaxf(sqrtf(ms), 1e-8f));
    if (sim > best) { best = sim; bidx = j; }  // strict > keeps first index
  }
  sred[t] = best;
  sidx[t] = bidx;
  __syncthreads();
  for (int s = 128; s > 0; s >>= 1) {
    if (t < s) {
      const float ov = sred[t + s];
      const int oi = sidx[t + s];
      if (ov > sred[t] || (ov == sred[t] && oi < sidx[t])) {
        sred[t] = ov;
        sidx[t] = oi;
      }
    }
    __syncthreads();
  }
  const float mx = sred[0];
  const int mi = sidx[0];
  if (t < CN)
    out[(size_t)q * CN + t] =
        (mx > 0.7f) ? labels[(size_t)mi * CN + t] : (1.0f / 128.0f);
}

extern "C" void kernel_launch(void* const* d_in, const int* in_sizes, int n_in,
                              void* d_out, int out_size, void* d_ws,
                              size_t ws_size, hipStream_t stream) {
  const float* qe = (const float*)d_in[0];  // [4096,384] f32
  const float* me = (const float*)d_in[1];  // [65536,384] f32
  const float* lb = (const float*)d_in[2];  // [65536,128] f32
  float* out = (float*)d_out;               // [4096,128] f32

  char* ws = (char*)d_ws;
  const size_t OFF_QN = 0;                  // qn4: 4096*192 = 786,432 B
  const size_t OFF_MN = OFF_QN + (size_t)QN * DN;        // mn4: 65536*192 B
  const size_t OFF_PMAX = OFF_MN + (size_t)MN * DN;      // (offsets roomy)
  unsigned char* qn4 = (unsigned char*)(ws + OFF_QN);    // fp4 fragment-major
  unsigned char* mn4 = (unsigned char*)(ws + OFF_MN);    // fp4 fragment-major
  float* pmax = (float*)(ws + OFF_PMAX);                 // [4096][64] = 1 MB

  nrm_kernel<<<(QN + MN) / 4, 256, 0, stream>>>(qe, me, qn4, mn4);
  gemm_max_kernel<<<dim3(QN / 128, NCHUNK), 256, 0, stream>>>(qn4, mn4, pmax);
  decide_kernel<<<QN, 256, 0, stream>>>(pmax, qe, me, lb, out);
}